// Round 10
// baseline (30.997 us; speedup 1.0000x reference)
//
#include <hip/hip_runtime.h>
#include <stdint.h>

// Problem: x (4096,2048) int32 {0,1}; references (1024,2048) f32 {0,1};
// out (4096,1024) f32 = (hamming - 1024) / (0.5*sqrt(2048)).
// Identity: with s=1-2x, t=1-2r in {+-1}, hamming = (2048 - s.t)/2, so
//   out[b,d] = -(inv_std/2) * dot_pm1(b,d)     (exact integer dot)
constexpr int B_ROWS = 4096;
constexpr int D_ROWS = 1024;
constexpr int L_LEN  = 2048;

using int32x4 = __attribute__((ext_vector_type(4))) int;

// ---------------------------------------------------------------------------
// Kernel 1 (UNCHANGED — control): convert both inputs to +-1 int8
// (0 -> 0x01, 1 -> 0xFF). Reads 16 B/lane coalesced, writes 4 B/lane.
// ~50 MB traffic -> ~8.5 us (near HBM floor, matches R5-pinned measurement).
// ---------------------------------------------------------------------------
__global__ __launch_bounds__(256) void convert_kernel(
    const int* __restrict__ x, const float* __restrict__ r,
    uint32_t* __restrict__ xq, uint32_t* __restrict__ rq,
    int groups_x, int groups_total)
{
  const int tid = blockIdx.x * blockDim.x + threadIdx.x;
  const int nth = gridDim.x * blockDim.x;
  for (int g = tid; g < groups_total; g += nth) {
    if (g < groups_x) {
      const int4 v = *reinterpret_cast<const int4*>(x + (size_t)g * 4);
      const uint32_t b0 = v.x ? 0xFFu : 0x01u;
      const uint32_t b1 = v.y ? 0xFFu : 0x01u;
      const uint32_t b2 = v.z ? 0xFFu : 0x01u;
      const uint32_t b3 = v.w ? 0xFFu : 0x01u;
      xq[g] = b0 | (b1 << 8) | (b2 << 16) | (b3 << 24);
    } else {
      const int gr = g - groups_x;
      const float4 v = *reinterpret_cast<const float4*>(r + (size_t)gr * 4);
      const uint32_t b0 = (v.x != 0.0f) ? 0xFFu : 0x01u;
      const uint32_t b1 = (v.y != 0.0f) ? 0xFFu : 0x01u;
      const uint32_t b2 = (v.z != 0.0f) ? 0xFFu : 0x01u;
      const uint32_t b3 = (v.w != 0.0f) ? 0xFFu : 0x01u;
      rq[gr] = b0 | (b1 << 8) | (b2 << 16) | (b3 << 24);
    }
  }
}

// ---------------------------------------------------------------------------
// Kernel 2 v3: i8 GEMM tuned for OCCUPANCY at this small shape.
//   BM=BN=64, BK=128 -> grid 1024 blocks = 4 blocks/CU = 4 waves/SIMD
//   (was 2/CU, 2/SIMD: latency-exposed; guide m102 shows the 128-tile
//   structure craters at small N for exactly this reason).
//   4 waves, wave grid 2x2, wave tile 32x32; mfma_i32_16x16x64_i8.
//   kk-OUTER MFMA order: 4 independent MFMAs per kk phase (was dependent
//   back-to-back pairs on the same acc).
//   Double-buffered LDS 2 x 16 KB; one barrier per K-step.
//   XOR-swizzle rule #21 (linear LDS dest, pre-swizzled source, swizzled
//   ds_read) -> 2-way conflicts only (free).
//   XCD-chunked bijective swizzle (T1): 1024 blocks % 8 == 0; each XCD gets
//   128 consecutive tiles = 8 A-panels (1 MB) + all B (2 MB) < 4 MB L2.
// ---------------------------------------------------------------------------
constexpr int BM = 64;
constexpr int BN = 64;
constexpr int BK = 128;
constexpr int KSTEPS = L_LEN / BK;   // 16
constexpr int GRID_D = D_ROWS / BN;  // 16
constexpr int NWG    = (B_ROWS / BM) * GRID_D;  // 1024

typedef __attribute__((address_space(3))) void       as3_void;
typedef const __attribute__((address_space(1))) void as1_cvoid;

__device__ __forceinline__ void gload_lds16(const void* g, void* l) {
  __builtin_amdgcn_global_load_lds((as1_cvoid*)g, (as3_void*)l, 16, 0, 0);
}

__global__ __launch_bounds__(256, 4) void gemm_i8_kernel(
    const char* __restrict__ Aq, const char* __restrict__ Bq,
    float* __restrict__ out)
{
  __shared__ __align__(16) char A_lds[2][BM * BK];   // 2 x 8 KB
  __shared__ __align__(16) char B_lds[2][BN * BK];   // 2 x 8 KB

  // XCD-chunked bijective remap (NWG % 8 == 0).
  const int lin = blockIdx.x;
  const int swz = (lin & 7) * (NWG / 8) + (lin >> 3);
  const int bm  = (swz / GRID_D) * BM;   // B-panel index varies slowly
  const int bn  = (swz % GRID_D) * BN;   // D sweeps fastest within a chunk

  const int t    = threadIdx.x;
  const int lane = t & 63;
  const int w    = t >> 6;          // wave 0..3
  const int wr   = w >> 1;          // wave row (m)
  const int wc   = w & 1;           // wave col (n)

  const int l8  = lane >> 3;        // row within 8-row staging group
  const int c16 = lane & 7;         // 16B slot within 128B row

  // Pre-swizzled per-lane global sources (rule #21). Wave w stages A rows
  // [w*16, w*16+16) and B rows [w*16, w*16+16); 2 gloads each.
  const char* gA[2];
  const char* gB[2];
#pragma unroll
  for (int c = 0; c < 2; ++c) {
    const int r = w * 16 + c * 8 + l8;
    gA[c] = Aq + (size_t)(bm + r) * L_LEN + ((c16 ^ (r & 7)) * 16);
    gB[c] = Bq + (size_t)(bn + r) * L_LEN + ((c16 ^ (r & 7)) * 16);
  }

#define STAGE(buf, k0) do {                                                   \
    _Pragma("unroll") for (int _c = 0; _c < 2; ++_c)                          \
      gload_lds16(gA[_c] + (k0), A_lds[buf] + (w * 16 + _c * 8) * BK);        \
    _Pragma("unroll") for (int _c = 0; _c < 2; ++_c)                          \
      gload_lds16(gB[_c] + (k0), B_lds[buf] + (w * 16 + _c * 8) * BK);        \
  } while (0)

  int32x4 acc[2][2] = {};           // 16 VGPR accumulator, static-indexed

  STAGE(0, 0);
  __syncthreads();

  for (int ks = 0; ks < KSTEPS; ++ks) {
    const int cur = ks & 1;
    if (ks + 1 < KSTEPS) STAGE(cur ^ 1, (ks + 1) * BK);   // prefetch in flight

    // Fragment reads (swizzled).
    int32x4 a[2][2], b[2][2];
#pragma unroll
    for (int kk = 0; kk < 2; ++kk) {
      const int kcol = kk * 64 + (lane >> 4) * 16;
#pragma unroll
      for (int f = 0; f < 2; ++f) {
        const int row = wr * 32 + f * 16 + (lane & 15);
        a[f][kk] = *reinterpret_cast<const int32x4*>(
            A_lds[cur] + row * BK + (kcol ^ ((row & 7) << 4)));
      }
#pragma unroll
      for (int gg = 0; gg < 2; ++gg) {
        const int row = wc * 32 + gg * 16 + (lane & 15);
        b[gg][kk] = *reinterpret_cast<const int32x4*>(
            B_lds[cur] + row * BK + (kcol ^ ((row & 7) << 4)));
      }
    }
    // kk-outer: 4 independent MFMAs per phase; acc-dependence distance = 4.
#pragma unroll
    for (int kk = 0; kk < 2; ++kk)
#pragma unroll
      for (int f = 0; f < 2; ++f)
#pragma unroll
        for (int gg = 0; gg < 2; ++gg)
          acc[f][gg] = __builtin_amdgcn_mfma_i32_16x16x64_i8(
              a[f][kk], b[gg][kk], acc[f][gg], 0, 0, 0);

    __syncthreads();   // single per-step drain
  }
#undef STAGE

  // Epilogue: C/D layout (verified): col = lane&15, row = (lane>>4)*4 + reg.
  const float scale = -0.5f * 0.04419417382415922f;
#pragma unroll
  for (int f = 0; f < 2; ++f) {
    const int brow = bm + wr * 32 + f * 16 + (lane >> 4) * 4;
#pragma unroll
    for (int gg = 0; gg < 2; ++gg) {
      const int d = bn + wc * 32 + gg * 16 + (lane & 15);
#pragma unroll
      for (int reg = 0; reg < 4; ++reg)
        out[(size_t)(brow + reg) * D_ROWS + d] = (float)acc[f][gg][reg] * scale;
    }
  }
}

extern "C" void kernel_launch(void* const* d_in, const int* in_sizes, int n_in,
                              void* d_out, int out_size, void* d_ws, size_t ws_size,
                              hipStream_t stream) {
  const int*   x = (const int*)d_in[0];     // (4096, 2048) int32
  const float* r = (const float*)d_in[1];   // (1024, 2048) float32
  float*     out = (float*)d_out;           // (4096, 1024) float32

  char* Aq = (char*)d_ws;                               // 8 MiB  (4096x2048 i8)
  char* Bq = Aq + (size_t)B_ROWS * L_LEN;               // 2 MiB  (1024x2048 i8)

  const int groups_x = B_ROWS * L_LEN / 4;              // 2097152
  const int groups_r = D_ROWS * L_LEN / 4;              // 524288
  const int groups_total = groups_x + groups_r;

  convert_kernel<<<2048, 256, 0, stream>>>(
      x, r, (uint32_t*)Aq, (uint32_t*)Bq, groups_x, groups_total);

  gemm_i8_kernel<<<NWG, 256, 0, stream>>>(Aq, Bq, out);  // 1024 blocks, 4/CU
}

// Round 11
// 27.380 us; speedup vs baseline: 1.1321x; 1.1321x over previous
//
#include <hip/hip_runtime.h>
#include <stdint.h>

// Problem: x (4096,2048) int32 {0,1}; references (1024,2048) f32 {0,1};
// out (4096,1024) f32 = (hamming - 1024) / (0.5*sqrt(2048)).
// Identity: with s=1-2x, t=1-2r in {+-1}, hamming = (2048 - s.t)/2, so
//   out[b,d] = -(inv_std/2) * dot_pm1(b,d)     (exact integer dot)
// fp4 E2M1 encodes +-1 exactly (+1=0x2, -1=0xA); with all MX scales = 1.0
// (E8M0 0x7F) the scaled MFMA computes the exact dot in f32.
constexpr int B_ROWS = 4096;
constexpr int D_ROWS = 1024;
constexpr int L_LEN  = 2048;
constexpr int LB     = L_LEN / 2;        // 1024 B per row at fp4

using int32x4 = __attribute__((ext_vector_type(4))) int;
using int32x8 = __attribute__((ext_vector_type(8))) int;
using f32x16  = __attribute__((ext_vector_type(16))) float;

// ---------------------------------------------------------------------------
// Kernel 1: convert both inputs to +-1 fp4, 2 elems/byte (elem 2j in low
// nibble). Nibble order is a K-permutation applied identically to A and B,
// so the dot is unaffected. Reads 32 B/thread, writes 4 B/thread coalesced.
// Traffic: 40 MB read + 5 MB write -> ~7.5 us.
// ---------------------------------------------------------------------------
__global__ __launch_bounds__(256) void convert_fp4_kernel(
    const int* __restrict__ x, const float* __restrict__ r,
    uint32_t* __restrict__ xq, uint32_t* __restrict__ rq,
    int groups_x, int groups_total)
{
  const int tid = blockIdx.x * blockDim.x + threadIdx.x;
  const int nth = gridDim.x * blockDim.x;
  for (int g = tid; g < groups_total; g += nth) {
    uint32_t wo;
    if (g < groups_x) {
      const int4 v0 = *reinterpret_cast<const int4*>(x + (size_t)g * 8);
      const int4 v1 = *reinterpret_cast<const int4*>(x + (size_t)g * 8 + 4);
      wo  = (v0.x ? 0xAu : 0x2u);
      wo |= (v0.y ? 0xAu : 0x2u) << 4;
      wo |= (v0.z ? 0xAu : 0x2u) << 8;
      wo |= (v0.w ? 0xAu : 0x2u) << 12;
      wo |= (v1.x ? 0xAu : 0x2u) << 16;
      wo |= (v1.y ? 0xAu : 0x2u) << 20;
      wo |= (v1.z ? 0xAu : 0x2u) << 24;
      wo |= (v1.w ? 0xAu : 0x2u) << 28;
      xq[g] = wo;
    } else {
      const int gr = g - groups_x;
      const float4 v0 = *reinterpret_cast<const float4*>(r + (size_t)gr * 8);
      const float4 v1 = *reinterpret_cast<const float4*>(r + (size_t)gr * 8 + 4);
      wo  = (v0.x != 0.0f ? 0xAu : 0x2u);
      wo |= (v0.y != 0.0f ? 0xAu : 0x2u) << 4;
      wo |= (v0.z != 0.0f ? 0xAu : 0x2u) << 8;
      wo |= (v0.w != 0.0f ? 0xAu : 0x2u) << 12;
      wo |= (v1.x != 0.0f ? 0xAu : 0x2u) << 16;
      wo |= (v1.y != 0.0f ? 0xAu : 0x2u) << 20;
      wo |= (v1.z != 0.0f ? 0xAu : 0x2u) << 24;
      wo |= (v1.w != 0.0f ? 0xAu : 0x2u) << 28;
      rq[gr] = wo;
    }
  }
}

// ---------------------------------------------------------------------------
// Kernel 2: MX-fp4 GEMM, R8's winning geometry (block 128x64, 4 waves 2x2,
// wave tile 64x32, BK=128 elems = 64 B, 2-phase dbuf, 1 barrier/step).
// mfma_scale_f32_32x32x64_f8f6f4, fmt=4/4 (FP4), scales fixed at 1.0.
// Per wave per K-step: 3 global_load_lds (1 KB each), 6 ds_read_b128,
// 4 MFMA (65536 FLOP each) -> 0.375 KB LDS per 32K FLOP (2x less than R8).
// LDS: rows are 64 B; phys slot p = q ^ ((row>>1)&3): a full-wave b128 read
// covers all 32 banks at exactly 8 accesses each (conflict-free floor).
// Staging: linear LDS dest (wave-uniform base + lane*16), inverse-swizzled
// global source (rule #21).
// Per-lane K-segment (lane>>5) and nibble order are identical permutations
// on A and B -> dot invariant; C/D layout = verified 32x32 mapping.
// ---------------------------------------------------------------------------
constexpr int BM = 128;
constexpr int BN = 64;
constexpr int BKB = 64;                  // K-step bytes per row (128 elems)
constexpr int KSTEPS = LB / BKB;         // 16
constexpr int GRID_D = D_ROWS / BN;      // 16
constexpr int NWG = (B_ROWS / BM) * GRID_D;   // 512

typedef __attribute__((address_space(3))) void       as3_void;
typedef const __attribute__((address_space(1))) void as1_cvoid;

__device__ __forceinline__ void gload_lds16(const void* g, void* l) {
  __builtin_amdgcn_global_load_lds((as1_cvoid*)g, (as3_void*)l, 16, 0, 0);
}

__global__ __launch_bounds__(256) void gemm_fp4_kernel(
    const uint8_t* __restrict__ Aq, const uint8_t* __restrict__ Bq,
    float* __restrict__ out)
{
  __shared__ __align__(16) uint8_t A_lds[2][BM * BKB];   // 2 x 8 KB
  __shared__ __align__(16) uint8_t B_lds[2][BN * BKB];   // 2 x 4 KB

  // Bijective XCD-chunked remap (NWG = 512, % 8 == 0). Per-XCD chunk:
  // 4 A-panels (512 KB fp4) + all B (1 MB) -> L2-resident.
  const int lin = blockIdx.x;
  const int swz = (lin & 7) * (NWG / 8) + (lin >> 3);
  const int bm  = (swz / GRID_D) * BM;
  const int bn  = (swz % GRID_D) * BN;

  const int t    = threadIdx.x;
  const int lane = t & 63;
  const int w    = t >> 6;          // wave 0..3
  const int wr   = w >> 1;          // wave row (m): tile rows wr*64..+64
  const int wc   = w & 1;           // wave col (n): tile cols wc*32..+32

  // Staging sources (pre-inverse-swizzled, rule #21). Each gload: 16 rows,
  // 4 lanes/row (16 B each). Dest is linear: uniform base + lane*16.
  //   A: wave stages rows [w*32, w*32+32) as 2 gloads; B: rows [w*16,+16).
  const uint8_t* gA[2];
#pragma unroll
  for (int c = 0; c < 2; ++c) {
    const int r = w * 32 + c * 16 + (lane >> 2);
    gA[c] = Aq + (size_t)(bm + r) * LB + (((lane & 3) ^ ((r >> 1) & 3)) * 16);
  }
  const int rB = w * 16 + (lane >> 2);
  const uint8_t* gB0 =
      Bq + (size_t)(bn + rB) * LB + (((lane & 3) ^ ((rB >> 1) & 3)) * 16);

#define STAGE(buf, k0b) do {                                                  \
    _Pragma("unroll") for (int _c = 0; _c < 2; ++_c)                          \
      gload_lds16(gA[_c] + (k0b), A_lds[buf] + (w * 32 + _c * 16) * BKB);     \
    gload_lds16(gB0 + (k0b), B_lds[buf] + (w * 16) * BKB);                    \
  } while (0)

  f32x16 acc[2] = {};               // 32 VGPR, static-indexed

  STAGE(0, 0);
  __syncthreads();

  for (int ks = 0; ks < KSTEPS; ++ks) {
    const int cur = ks & 1;
    if (ks + 1 < KSTEPS) STAGE(cur ^ 1, (ks + 1) * BKB);   // in flight

    // kc = MFMA K-chunk (64 elems = 32 B = 2 slots); lane>>5 picks the slot.
#pragma unroll
    for (int kc = 0; kc < 2; ++kc) {
      const int rowB  = wc * 32 + (lane & 31);
      const int qB    = 2 * kc + (lane >> 5);
      const int32x4 b4 = *reinterpret_cast<const int32x4*>(
          B_lds[cur] + rowB * BKB + ((qB ^ ((rowB >> 1) & 3)) * 16));
      const int32x8 b8 = {b4[0], b4[1], b4[2], b4[3], 0, 0, 0, 0};
#pragma unroll
      for (int f = 0; f < 2; ++f) {
        const int rowA  = wr * 64 + f * 32 + (lane & 31);
        const int qA    = 2 * kc + (lane >> 5);
        const int32x4 a4 = *reinterpret_cast<const int32x4*>(
            A_lds[cur] + rowA * BKB + ((qA ^ ((rowA >> 1) & 3)) * 16));
        const int32x8 a8 = {a4[0], a4[1], a4[2], a4[3], 0, 0, 0, 0};
        // fmt codes: FP4 = 4 for both; scales = E8M0 1.0 (0x7F), opsel 0.
        acc[f] = __builtin_amdgcn_mfma_scale_f32_32x32x64_f8f6f4(
            a8, b8, acc[f], 4, 4, 0, 0x7F7F7F7F, 0, 0x7F7F7F7F);
      }
    }
    __syncthreads();   // single per-step drain
  }
#undef STAGE

  // Epilogue: 32x32 C/D layout (verified, shape-determined):
  // col = lane&31, row = (reg&3) + 8*(reg>>2) + 4*(lane>>5).
  const float scale = -0.5f * 0.04419417382415922f;
  const int col = bn + wc * 32 + (lane & 31);
#pragma unroll
  for (int f = 0; f < 2; ++f) {
#pragma unroll
    for (int reg = 0; reg < 16; ++reg) {
      const int row = bm + wr * 64 + f * 32 + (reg & 3) + 8 * (reg >> 2)
                    + 4 * (lane >> 5);
      out[(size_t)row * D_ROWS + col] = acc[f][reg] * scale;
    }
  }
}

extern "C" void kernel_launch(void* const* d_in, const int* in_sizes, int n_in,
                              void* d_out, int out_size, void* d_ws, size_t ws_size,
                              hipStream_t stream) {
  const int*   x = (const int*)d_in[0];     // (4096, 2048) int32
  const float* r = (const float*)d_in[1];   // (1024, 2048) float32
  float*     out = (float*)d_out;           // (4096, 1024) float32

  uint8_t* Aq = (uint8_t*)d_ws;                         // 4 MiB (4096x1024 B)
  uint8_t* Bq = Aq + (size_t)B_ROWS * LB;               // 1 MiB (1024x1024 B)

  const int groups_x = B_ROWS * L_LEN / 8;              // 1048576
  const int groups_r = D_ROWS * L_LEN / 8;              // 262144
  const int groups_total = groups_x + groups_r;

  convert_fp4_kernel<<<2048, 256, 0, stream>>>(
      x, r, (uint32_t*)Aq, (uint32_t*)Bq, groups_x, groups_total);

  gemm_fp4_kernel<<<NWG, 256, 0, stream>>>(Aq, Bq, out);  // 512 blocks
}

// Round 12
// 25.022 us; speedup vs baseline: 1.2388x; 1.0942x over previous
//
#include <hip/hip_runtime.h>
#include <stdint.h>

// Problem: x (4096,2048) int32 {0,1}; references (1024,2048) f32 {0,1};
// out (4096,1024) f32 = (hamming - 1024) / (0.5*sqrt(2048)).
// Identity: with s=1-2x, t=1-2r in {+-1}, hamming = (2048 - s.t)/2, so
//   out[b,d] = -(inv_std/2) * dot_pm1(b,d)     (exact integer dot)
// fp4 E2M1 encodes +-1 exactly (+1=0x2, -1=0xA); all MX scales = 1.0 (0x7F).
constexpr int B_ROWS = 4096;
constexpr int D_ROWS = 1024;
constexpr int L_LEN  = 2048;
constexpr int LB     = L_LEN / 2;        // 1024 B per row at fp4

using int32x4 = __attribute__((ext_vector_type(4))) int;
using int32x8 = __attribute__((ext_vector_type(8))) int;
using f32x16  = __attribute__((ext_vector_type(16))) float;

// ---------------------------------------------------------------------------
// Kernel 1 (UNCHANGED — control): convert both inputs to +-1 fp4.
// ---------------------------------------------------------------------------
__global__ __launch_bounds__(256) void convert_fp4_kernel(
    const int* __restrict__ x, const float* __restrict__ r,
    uint32_t* __restrict__ xq, uint32_t* __restrict__ rq,
    int groups_x, int groups_total)
{
  const int tid = blockIdx.x * blockDim.x + threadIdx.x;
  const int nth = gridDim.x * blockDim.x;
  for (int g = tid; g < groups_total; g += nth) {
    uint32_t wo;
    if (g < groups_x) {
      const int4 v0 = *reinterpret_cast<const int4*>(x + (size_t)g * 8);
      const int4 v1 = *reinterpret_cast<const int4*>(x + (size_t)g * 8 + 4);
      wo  = (v0.x ? 0xAu : 0x2u);
      wo |= (v0.y ? 0xAu : 0x2u) << 4;
      wo |= (v0.z ? 0xAu : 0x2u) << 8;
      wo |= (v0.w ? 0xAu : 0x2u) << 12;
      wo |= (v1.x ? 0xAu : 0x2u) << 16;
      wo |= (v1.y ? 0xAu : 0x2u) << 20;
      wo |= (v1.z ? 0xAu : 0x2u) << 24;
      wo |= (v1.w ? 0xAu : 0x2u) << 28;
      xq[g] = wo;
    } else {
      const int gr = g - groups_x;
      const float4 v0 = *reinterpret_cast<const float4*>(r + (size_t)gr * 8);
      const float4 v1 = *reinterpret_cast<const float4*>(r + (size_t)gr * 8 + 4);
      wo  = (v0.x != 0.0f ? 0xAu : 0x2u);
      wo |= (v0.y != 0.0f ? 0xAu : 0x2u) << 4;
      wo |= (v0.z != 0.0f ? 0xAu : 0x2u) << 8;
      wo |= (v0.w != 0.0f ? 0xAu : 0x2u) << 12;
      wo |= (v1.x != 0.0f ? 0xAu : 0x2u) << 16;
      wo |= (v1.y != 0.0f ? 0xAu : 0x2u) << 20;
      wo |= (v1.z != 0.0f ? 0xAu : 0x2u) << 24;
      wo |= (v1.w != 0.0f ? 0xAu : 0x2u) << 28;
      rq[gr] = wo;
    }
  }
}

// ---------------------------------------------------------------------------
// Kernel 2 v2: MX-fp4 GEMM with T4 counted-vmcnt pipeline.
//   Same geometry as R11 (block 128x64, 4 waves 2x2, wave tile 64x32,
//   BK=128 elems = 64 B, mfma_scale_f32_32x32x64_f8f6f4 fmt 4/4).
//   NEW: 3 LDS buffers, 2 tiles in flight, raw s_barrier + inline-asm
//   s_waitcnt vmcnt(3) (NEVER 0 in the main loop). Per step ks:
//     vmcnt(3)   -> own tile-ks loads (3 gloads) landed; ks+1's stay flying
//     s_barrier  -> every wave's tile-ks stores visible; also proves all
//                   waves finished step ks-1's compute
//     STAGE((ks+2)%3) -> overwrites the buffer READ at step ks-1; safe
//                   because the barrier just proved those reads are done,
//                   and our own old loads to it completed at step ks-1's
//                   vmcnt. Wave-staged regions are disjoint.
//     compute tile ks (6 ds_read_b128 + 4 MFMA)
//   One barrier/step; the vmcnt(0)+lgkmcnt(0) full drain that __syncthreads
//   emitted each step (the serial ~600cyc/step chain = the 19us) is gone.
//   sched_barrier(0) after each waitcnt per guide rule #18.
//   LDS 3 x 12 KB = 36 KB. Peeled last step uses vmcnt(0).
// ---------------------------------------------------------------------------
constexpr int BM = 128;
constexpr int BN = 64;
constexpr int BKB = 64;                  // K-step bytes per row (128 elems)
constexpr int KSTEPS = LB / BKB;         // 16
constexpr int GRID_D = D_ROWS / BN;      // 16
constexpr int NWG = (B_ROWS / BM) * GRID_D;   // 512

typedef __attribute__((address_space(3))) void       as3_void;
typedef const __attribute__((address_space(1))) void as1_cvoid;

__device__ __forceinline__ void gload_lds16(const void* g, void* l) {
  __builtin_amdgcn_global_load_lds((as1_cvoid*)g, (as3_void*)l, 16, 0, 0);
}

__global__ __launch_bounds__(256) void gemm_fp4_kernel(
    const uint8_t* __restrict__ Aq, const uint8_t* __restrict__ Bq,
    float* __restrict__ out)
{
  __shared__ __align__(16) uint8_t A_lds[3][BM * BKB];   // 3 x 8 KB
  __shared__ __align__(16) uint8_t B_lds[3][BN * BKB];   // 3 x 4 KB

  // Bijective XCD-chunked remap (NWG = 512 % 8 == 0): per-XCD chunk reads
  // 4 A-panels (512 KB) + all B (1 MB) -> L2-resident.
  const int lin = blockIdx.x;
  const int swz = (lin & 7) * (NWG / 8) + (lin >> 3);
  const int bm  = (swz / GRID_D) * BM;
  const int bn  = (swz % GRID_D) * BN;

  const int t    = threadIdx.x;
  const int lane = t & 63;
  const int w    = t >> 6;          // wave 0..3
  const int wr   = w >> 1;          // wave row (m): tile rows wr*64..+64
  const int wc   = w & 1;           // wave col (n): tile cols wc*32..+32

  // Staging sources (pre-inverse-swizzled, rule #21): 16 rows, 4 lanes/row,
  // linear LDS dest (uniform base + lane*16). LDS swizzle: phys 16B slot
  // q ^ ((row>>1)&3) -> full-wave b128 read = 8 accesses/bank (floor).
  const uint8_t* gA[2];
#pragma unroll
  for (int c = 0; c < 2; ++c) {
    const int r = w * 32 + c * 16 + (lane >> 2);
    gA[c] = Aq + (size_t)(bm + r) * LB + (((lane & 3) ^ ((r >> 1) & 3)) * 16);
  }
  const int rB = w * 16 + (lane >> 2);
  const uint8_t* gB0 =
      Bq + (size_t)(bn + rB) * LB + (((lane & 3) ^ ((rB >> 1) & 3)) * 16);

#define STAGE(buf, k0b) do {                                                  \
    _Pragma("unroll") for (int _c = 0; _c < 2; ++_c)                          \
      gload_lds16(gA[_c] + (k0b), A_lds[buf] + (w * 32 + _c * 16) * BKB);     \
    gload_lds16(gB0 + (k0b), B_lds[buf] + (w * 16) * BKB);                    \
  } while (0)

#define COMPUTE(cur) do {                                                     \
    _Pragma("unroll") for (int kc = 0; kc < 2; ++kc) {                        \
      const int rowB = wc * 32 + (lane & 31);                                 \
      const int qB   = 2 * kc + (lane >> 5);                                  \
      const int32x4 b4 = *reinterpret_cast<const int32x4*>(                   \
          B_lds[cur] + rowB * BKB + ((qB ^ ((rowB >> 1) & 3)) * 16));         \
      const int32x8 b8 = {b4[0], b4[1], b4[2], b4[3], 0, 0, 0, 0};            \
      _Pragma("unroll") for (int f = 0; f < 2; ++f) {                         \
        const int rowA = wr * 64 + f * 32 + (lane & 31);                      \
        const int qA   = 2 * kc + (lane >> 5);                                \
        const int32x4 a4 = *reinterpret_cast<const int32x4*>(                 \
            A_lds[cur] + rowA * BKB + ((qA ^ ((rowA >> 1) & 3)) * 16));       \
        const int32x8 a8 = {a4[0], a4[1], a4[2], a4[3], 0, 0, 0, 0};          \
        acc[f] = __builtin_amdgcn_mfma_scale_f32_32x32x64_f8f6f4(             \
            a8, b8, acc[f], 4, 4, 0, 0x7F7F7F7F, 0, 0x7F7F7F7F);              \
      }                                                                       \
    } } while (0)

  f32x16 acc[2] = {};               // 32 VGPR, static-indexed

  STAGE(0, 0);
  STAGE(1, BKB);                    // 6 loads in flight

#pragma unroll 3
  for (int ks = 0; ks < KSTEPS - 1; ++ks) {   // 15 iters, cur/(ks+2)%3 static
    const int cur = ks % 3;
    asm volatile("s_waitcnt vmcnt(3)" ::: "memory");  // tile ks landed
    __builtin_amdgcn_sched_barrier(0);                // rule #18
    __builtin_amdgcn_s_barrier();                     // raw: no vmcnt(0) drain
    if (ks + 2 < KSTEPS) STAGE((ks + 2) % 3, (ks + 2) * BKB);
    COMPUTE(cur);
  }
  // Peeled final step (ks = 15, cur = 15 % 3 = 0): drain the last tile.
  asm volatile("s_waitcnt vmcnt(0)" ::: "memory");
  __builtin_amdgcn_sched_barrier(0);
  __builtin_amdgcn_s_barrier();
  COMPUTE(0);

#undef STAGE
#undef COMPUTE

  // Epilogue: 32x32 C/D layout (verified, shape-determined):
  // col = lane&31, row = (reg&3) + 8*(reg>>2) + 4*(lane>>5).
  const float scale = -0.5f * 0.04419417382415922f;
  const int col = bn + wc * 32 + (lane & 31);
#pragma unroll
  for (int f = 0; f < 2; ++f) {
#pragma unroll
    for (int reg = 0; reg < 16; ++reg) {
      const int row = bm + wr * 64 + f * 32 + (reg & 3) + 8 * (reg >> 2)
                    + 4 * (lane >> 5);
      out[(size_t)row * D_ROWS + col] = acc[f][reg] * scale;
    }
  }
}

extern "C" void kernel_launch(void* const* d_in, const int* in_sizes, int n_in,
                              void* d_out, int out_size, void* d_ws, size_t ws_size,
                              hipStream_t stream) {
  const int*   x = (const int*)d_in[0];     // (4096, 2048) int32
  const float* r = (const float*)d_in[1];   // (1024, 2048) float32
  float*     out = (float*)d_out;           // (4096, 1024) float32

  uint8_t* Aq = (uint8_t*)d_ws;                         // 4 MiB (4096x1024 B)
  uint8_t* Bq = Aq + (size_t)B_ROWS * LB;               // 1 MiB (1024x1024 B)

  const int groups_x = B_ROWS * L_LEN / 8;              // 1048576
  const int groups_r = D_ROWS * L_LEN / 8;              // 262144
  const int groups_total = groups_x + groups_r;

  convert_fp4_kernel<<<2048, 256, 0, stream>>>(
      x, r, (uint32_t*)Aq, (uint32_t*)Bq, groups_x, groups_total);

  gemm_fp4_kernel<<<NWG, 256, 0, stream>>>(Aq, Bq, out);  // 512 blocks
}